// Round 8
// baseline (11873.830 us; speedup 1.0000x reference)
//
#include <hip/hip_runtime.h>
#include <stdint.h>

typedef unsigned long long u64;
typedef u64 u64x2 __attribute__((ext_vector_type(2)));

#define VOCAB 128
#define RD 128
#define DM 1024
#define NFF 6
#define BATCH 64
#define TSTEPS 512

// ---------------------------------------------------------------------------
// ws layout:
//   [0, 786432)          ffb2   [L][wp][j][2] u64  (L<6, wp<8, j<1024, s<2)
//                        u64 index = ((L*8+wp)<<11) + (j<<1) + s
//   [786432, +2048)      ebits  [v][2]    u64   (v<128)
//   [788480, +2048)      headb  [v][2]    u64   (v<128)
//   [790528, +512)       losses [64]      double
// ---------------------------------------------------------------------------

// lgkm-only barrier: LDS writes drained, global (vmcnt) weight prefetch stays
// in flight across the barrier.
#define BARRIER()                                            \
    do {                                                     \
        asm volatile("s_waitcnt lgkmcnt(0)" ::: "memory");   \
        __builtin_amdgcn_s_barrier();                        \
    } while (0)

// Pack ff sign bits into the pair layout: word pair (2wp, 2wp+1) of column j,
// bit b of word w = (ff[L][w*64+b][j] < 0)  (1 => -1)
__global__ void pack_ff(const float* __restrict__ ff, u64* __restrict__ ffb2) {
    int wid  = blockIdx.x * (blockDim.x >> 6) + (threadIdx.x >> 6); // 0..1535
    int lane = threadIdx.x & 63;
    int jt = wid & 15;
    int w  = (wid >> 4) & 15;  // word index 0..15
    int i  = wid >> 8;         // layer
    int j  = jt * 64 + lane;
    const float* src = ff + ((size_t)(i * DM) + w * 64) * DM + j;
    u64 word = 0;
#pragma unroll
    for (int b = 0; b < 64; ++b) {
        float v = src[(size_t)b * DM];
        word |= (u64)(v < 0.0f) << b;
    }
    ffb2[(((size_t)i * 8 + (w >> 1)) << 11) + (j << 1) + (w & 1)] = word;
}

// Pack embed rows and head columns (tiny).
__global__ void pack_small(const float* __restrict__ emb, const float* __restrict__ head,
                           u64* __restrict__ eb, u64* __restrict__ hb) {
    int tid = threadIdx.x; // 0..255
    if (tid < 128) {
        int v = tid;
        for (int wd = 0; wd < 2; ++wd) {
            u64 word = 0;
            for (int l = 0; l < 64; ++l)
                word |= (u64)(emb[v * RD + wd * 64 + l] < 0.0f) << l;
            eb[v * 2 + wd] = word;
        }
    } else {
        int v = tid - 128;
        for (int wd = 0; wd < 2; ++wd) {
            u64 word = 0;
            for (int l = 0; l < 64; ++l)
                word |= (u64)(head[(wd * 64 + l) * VOCAB + v] < 0.0f) << l;
            hb[v * 2 + wd] = word;
        }
    }
}

// Issue 8 nontemporal dwordx4 loads for layer L's column `tid` into BUF
// (fully unrolled constant indices -> registers).
#define PREFETCH(BUF, L)                                                 \
    do {                                                                 \
        const u64x2* wb_ = wbase + (((L) * 8) << 10) + tid;              \
        _Pragma("unroll")                                                \
        for (int k_ = 0; k_ < 8; ++k_) {                                 \
            u64x2 v_ = __builtin_nontemporal_load(wb_ + (k_ << 10));     \
            BUF[2 * k_] = v_.x; BUF[2 * k_ + 1] = v_.y;                  \
        }                                                                \
    } while (0)

// One binary FF layer from register buffer CBUF and LDS h at parity SRC;
// ballot result written to parity DST.
#define LAYER(SRC, DST, CBUF, ITH)                                       \
    do {                                                                 \
        const ulonglong2* hp_ = (const ulonglong2*)hbuf[SRC];            \
        int acc_ = 0;                                                    \
        _Pragma("unroll")                                                \
        for (int q_ = 0; q_ < 8; ++q_) {                                 \
            ulonglong2 hv_ = hp_[q_]; /* broadcast ds_read_b128 */       \
            acc_ += __popcll(hv_.x ^ CBUF[2 * q_]) +                     \
                    __popcll(hv_.y ^ CBUF[2 * q_ + 1]);                  \
        }                                                                \
        u64 m_ = __ballot(acc_ >= cthr[ITH]);                            \
        if (lane == 0) hbuf[DST][wv] = m_;                               \
        BARRIER();                                                       \
    } while (0)

// Main recurrent kernel: one block per batch row, thread j owns column j.
// Weights stream from L2 with one-layer-ahead register double-buffering
// (cA/cB ping-pong, no rotate -> vmcnt wait lands a full layer after issue).
// 96 KB LDS forces 1 block/CU, so occupancy is LDS-capped at 4 waves/SIMD
// and the allocator may use the full 128-VGPR budget (no spill).
__global__ void __launch_bounds__(1024, 4)
brnn_main(const int* __restrict__ tokens,
          const float* __restrict__ initial_lat,
          const float* __restrict__ thr_lat,
          const u64* __restrict__ ffb2,
          const u64* __restrict__ eb,
          const u64* __restrict__ hb,
          double* __restrict__ losses) {
    const int b    = blockIdx.x;
    const int tid  = threadIdx.x;
    const int lane = tid & 63;
    const int wv   = tid >> 6;

    // 96 KB LDS: occupancy limiter (1 block/CU). First words used for h + head.
    __shared__ __align__(16) u64 smem[12288];
    u64 (*hbuf)[16] = (u64 (*)[16])smem;     // smem[0..31]: h ping-pong
    u64* hbL = smem + 32;                    // smem[32..287]: head bits

    const u64x2* wbase = (const u64x2*)ffb2;

    if (tid < 2 * VOCAB) hbL[tid] = hb[tid];

    // thresholds -> popcount cutoffs:  bit(-1) <=> pre < thr  <=>  acc >= cthr
    int cthr[NFF];
#pragma unroll
    for (int i = 0; i < NFF; ++i) {
        int thr = (int)rintf(thr_lat[i * DM + tid]); // round-half-even == jnp.round
        cthr[i] = ((DM - thr) >> 1) + 1;
    }

    // register double-buffers for one layer's weights (this thread's column)
    u64 cA[16], cB[16];
    PREFETCH(cA, 0);

    // --- init h = sign(initial_lat), into buffer 0 ---
    {
        u64 m = __ballot(initial_lat[tid] < 0.0f);
        if (lane == 0) hbuf[0][wv] = m;
    }
    BARRIER();

    const int* toks = tokens + b * TSTEPS;
    double lacc = 0.0;

    for (int t = 0; t < TSTEPS; ++t) {
        int tok = toks[t]; // uniform -> scalar load

        // prefetch embed bits for the end-of-step splice (hides under 6 layers)
        u64 enew = 0;
        if (wv == 0 && lane < 2) enew = eb[tok * 2 + lane];

        // --- 6 binary FF layers, ping-pong cA/cB, prefetch one layer ahead ---
        PREFETCH(cB, 1); LAYER(0, 1, cA, 0);
        PREFETCH(cA, 2); LAYER(1, 0, cB, 1);
        PREFETCH(cB, 3); LAYER(0, 1, cA, 2);
        PREFETCH(cA, 4); LAYER(1, 0, cB, 3);
        PREFETCH(cB, 5); LAYER(0, 1, cA, 4);
        PREFETCH(cA, 0); LAYER(1, 0, cB, 5);   // layer 0 again for t+1

        // --- head + log-softmax + loss + embed splice (wave 0); h5 in hbuf[0] ---
        if (wv == 0) {
            u64 r0 = hbuf[0][14], r1 = hbuf[0][15];
            u64 h0a = hbL[lane * 2 + 0],        h0b = hbL[lane * 2 + 1];
            u64 h1a = hbL[(lane + 64) * 2 + 0], h1b = hbL[(lane + 64) * 2 + 1];
            int d0 = 128 - 2 * (__popcll(r0 ^ h0a) + __popcll(r1 ^ h0b));
            int d1 = 128 - 2 * (__popcll(r0 ^ h1a) + __popcll(r1 ^ h1b));
            float l0 = (float)d0 * (1.0f / 16.0f);
            float l1 = (float)d1 * (1.0f / 16.0f);
            float mx = fmaxf(l0, l1);
#pragma unroll
            for (int s = 32; s >= 1; s >>= 1) mx = fmaxf(mx, __shfl_xor(mx, s));
            float se = __expf(l0 - mx) + __expf(l1 - mx);
#pragma unroll
            for (int s = 32; s >= 1; s >>= 1) se += __shfl_xor(se, s);
            int   tl   = tok & 63;
            float la   = __shfl(l0, tl);
            float lb   = __shfl(l1, tl);
            float ltok = (tok >> 6) ? lb : la;
            lacc += (double)(mx + __logf(se) - ltok);
            // splice x_new read-part = sign(embed[tok]) into words 14,15
            if (lane < 2) hbuf[0][14 + lane] = enew;
        }
        BARRIER();
    }

    if (tid == 0) losses[b] = lacc;
}

__global__ void reduce_loss(const double* __restrict__ losses, float* __restrict__ out) {
    int lane = threadIdx.x; // 64 threads, 1 wave
    double v = losses[lane];
#pragma unroll
    for (int s = 32; s >= 1; s >>= 1) v += __shfl_down(v, s);
    if (lane == 0) out[0] = (float)(v * (1.0 / ((double)BATCH * (double)TSTEPS)));
}

extern "C" void kernel_launch(void* const* d_in, const int* in_sizes, int n_in,
                              void* d_out, int out_size, void* d_ws, size_t ws_size,
                              hipStream_t stream) {
    const int*   tokens  = (const int*)d_in[0];   // (64, 512) int32
    const float* initial = (const float*)d_in[1]; // (1024,)
    const float* embed   = (const float*)d_in[2]; // (128, 128)
    const float* ff      = (const float*)d_in[3]; // (6, 1024, 1024)
    const float* head    = (const float*)d_in[4]; // (128, 128)
    const float* thrl    = (const float*)d_in[5]; // (6, 1024)

    char* ws = (char*)d_ws;
    u64*    ffb2   = (u64*)ws;                      // 786432 B
    u64*    eb     = (u64*)(ws + 786432);           // 2048 B
    u64*    hb     = (u64*)(ws + 786432 + 2048);    // 2048 B
    double* losses = (double*)(ws + 786432 + 4096); // 512 B

    pack_ff<<<384, 256, 0, stream>>>(ff, ffb2);
    pack_small<<<1, 256, 0, stream>>>(embed, head, eb, hb);
    brnn_main<<<BATCH, 1024, 0, stream>>>(tokens, initial, thrl, ffb2, eb, hb, losses);
    reduce_loss<<<1, 64, 0, stream>>>(losses, (float*)d_out);
}

// Round 10
// 6476.649 us; speedup vs baseline: 1.8333x; 1.8333x over previous
//
#include <hip/hip_runtime.h>
#include <stdint.h>

typedef unsigned long long u64;
typedef uint32_t u32;

#define VOCAB 128
#define RD 128
#define DM 1024
#define NFF 6
#define BATCH 64
#define TSTEPS 512
#define NLOC 3    // layers per pipeline stage
#define THR 256   // threads per block; thread owns cols tid+256c, c=0..3

// ---------------------------------------------------------------------------
// ws layout (bytes):
//   [0,        786432)  ffbits [L][w][j] u64  (L<6, w<16, j<1024)
//   [786432,  +2048)    ebits  [v][2]    u64
//   [788480,  +2048)    headb  [v][2]    u64
//   [790528,  +512)     losses [64]      double
//   [791040,  +8192)    xbuf   [64][16]  u64  (x for next step, written by B)
//   [799232,  +8192)    mbuf   [64][16]  u64  (mid h after layer 2, by A)
//   [807424,  +256)     fA     [64]      u32
//   [807680,  +256)     fB     [64]      u32
// ---------------------------------------------------------------------------
#define OFF_EB    786432
#define OFF_HB    788480
#define OFF_LOSS  790528
#define OFF_XBUF  791040
#define OFF_MBUF  799232
#define OFF_FA    807424
#define OFF_FB    807680

__device__ __forceinline__ void wait_ge(const u32* f, u32 target) {
    while (__hip_atomic_load(f, __ATOMIC_ACQUIRE, __HIP_MEMORY_SCOPE_AGENT) < target)
        __builtin_amdgcn_s_sleep(1);
}

// Pack ff sign bits: bit b of word (L,w,j) = (ff[L][w*64+b][j] < 0)  (1 => -1)
__global__ void pack_ff(const float* __restrict__ ff, u64* __restrict__ ffb) {
    int wid  = blockIdx.x * (blockDim.x >> 6) + (threadIdx.x >> 6); // 0..1535
    int lane = threadIdx.x & 63;
    int jt = wid & 15;
    int w  = (wid >> 4) & 15;
    int i  = wid >> 8;
    int j  = jt * 64 + lane;
    const float* src = ff + ((size_t)(i * DM) + w * 64) * DM + j;
    u64 word = 0;
#pragma unroll
    for (int b = 0; b < 64; ++b) {
        float v = src[(size_t)b * DM];
        word |= (u64)(v < 0.0f) << b;
    }
    ffb[((i * 16 + w) << 10) + j] = word;
}

__global__ void pack_small(const float* __restrict__ emb, const float* __restrict__ head,
                           u64* __restrict__ eb, u64* __restrict__ hb) {
    int tid = threadIdx.x; // 0..255
    if (tid < 128) {
        int v = tid;
        for (int wd = 0; wd < 2; ++wd) {
            u64 word = 0;
            for (int l = 0; l < 64; ++l)
                word |= (u64)(emb[v * RD + wd * 64 + l] < 0.0f) << l;
            eb[v * 2 + wd] = word;
        }
    } else {
        int v = tid - 128;
        for (int wd = 0; wd < 2; ++wd) {
            u64 word = 0;
            for (int l = 0; l < 64; ++l)
                word |= (u64)(head[(wd * 64 + l) * VOCAB + v] < 0.0f) << l;
            hb[v * 2 + wd] = word;
        }
    }
}

// One binary FF layer over this block's 3 resident layers. L is a LITERAL
// (compile-time) index into fr/cthr so everything stays in registers.
// Thread owns cols j = c*256 + tid; ballot word index = c*4 + wv.
#define PASS(P, L, EMIT) do {                                                   \
    const ulonglong2* hp_ = (const ulonglong2*)hx[P];                           \
    int a0_ = 0, a1_ = 0, a2_ = 0, a3_ = 0;                                     \
    _Pragma("unroll")                                                           \
    for (int q_ = 0; q_ < 8; ++q_) {                                            \
        ulonglong2 hv_ = hp_[q_]; /* broadcast ds_read_b128 */                  \
        a0_ += __popcll(hv_.x ^ fr[L][0][2*q_]) + __popcll(hv_.y ^ fr[L][0][2*q_+1]); \
        a1_ += __popcll(hv_.x ^ fr[L][1][2*q_]) + __popcll(hv_.y ^ fr[L][1][2*q_+1]); \
        a2_ += __popcll(hv_.x ^ fr[L][2][2*q_]) + __popcll(hv_.y ^ fr[L][2][2*q_+1]); \
        a3_ += __popcll(hv_.x ^ fr[L][3][2*q_]) + __popcll(hv_.y ^ fr[L][3][2*q_+1]); \
    }                                                                           \
    u64 m0_ = __ballot(a0_ >= cthr[L][0]);                                      \
    u64 m1_ = __ballot(a1_ >= cthr[L][1]);                                      \
    u64 m2_ = __ballot(a2_ >= cthr[L][2]);                                      \
    u64 m3_ = __ballot(a3_ >= cthr[L][3]);                                      \
    EMIT;                                                                       \
    __syncthreads();                                                            \
} while (0)

// Pipelined main kernel: 64 blocks x 256 threads, 1 wave/SIMD
// (amdgpu_waves_per_eu(1,1) -> 512-reg budget/wave; weights 384 regs RESIDENT).
// Blocks 0..31 = stage A (layers 0-2) for rows {2g,2g+1};
// blocks 32..63 = stage B (layers 3-5 + head/loss/splice).
// Pair (g, g+32) shares an XCD (32 % 8 == 0) -> L2-local handoff.
__global__ void
__attribute__((amdgpu_flat_work_group_size(256, 256), amdgpu_waves_per_eu(1, 1)))
brnn_pipe(const int* __restrict__ tokens,
          const float* __restrict__ initial_lat,
          const float* __restrict__ thr_lat,
          const u64* __restrict__ ffb,
          const u64* __restrict__ eb,
          const u64* __restrict__ hb,
          u64* __restrict__ xbuf, u64* __restrict__ mbuf,
          u32* __restrict__ fA, u32* __restrict__ fB,
          double* __restrict__ losses)
{
    const int blk  = blockIdx.x;
    const int role = blk >> 5; // 0 = A, 1 = B
    const int g    = blk & 31;
    const int tid  = threadIdx.x;
    const int lane = tid & 63;
    const int wv   = tid >> 6; // 0..3

    __shared__ __align__(16) u64 hx[2][16];
    __shared__ u64 hbL[2 * VOCAB];

    const int lbase = role * NLOC;

    // --- resident packed weights: 3 layers x 4 cols x 16 u64 = 384 regs ---
    u64 fr[NLOC][4][16];
#pragma unroll
    for (int l = 0; l < NLOC; ++l)
#pragma unroll
        for (int c = 0; c < 4; ++c)
#pragma unroll
            for (int w = 0; w < 16; ++w)
                fr[l][c][w] = ffb[(((lbase + l) * 16 + w) << 10) + c * THR + tid];

    // thresholds -> popcount cutoffs:  bit(-1) <=> popcnt >= cthr
    int cthr[NLOC][4];
#pragma unroll
    for (int l = 0; l < NLOC; ++l)
#pragma unroll
        for (int c = 0; c < 4; ++c) {
            int th = (int)rintf(thr_lat[(lbase + l) * DM + c * THR + tid]);
            cthr[l][c] = ((DM - th) >> 1) + 1;
        }

    if (role == 1 && tid < 2 * VOCAB) hbL[tid] = hb[tid];

    double lacc0 = 0.0, lacc1 = 0.0;
    const int r0 = 2 * g;

    if (role == 0) {
        // ------------------------- stage A: layers 0-2 -------------------------
        for (int t = 0; t < TSTEPS; ++t) {
#pragma unroll
            for (int ri = 0; ri < 2; ++ri) {
                const int r = r0 + ri;
                if (t == 0) {
#pragma unroll
                    for (int c = 0; c < 4; ++c) {
                        u64 m = __ballot(initial_lat[c * THR + tid] < 0.0f);
                        if (lane == 0) hx[0][c * 4 + wv] = m;
                    }
                } else {
                    wait_ge(&fB[r], (u32)t); // acquire: xbuf fresh
                    if (wv == 0 && lane < 16) hx[0][lane] = xbuf[r * 16 + lane];
                }
                __syncthreads();
                PASS(0, 0, if (lane == 0) { hx[1][wv] = m0_; hx[1][4 + wv] = m1_;
                                            hx[1][8 + wv] = m2_; hx[1][12 + wv] = m3_; });
                PASS(1, 1, if (lane == 0) { hx[0][wv] = m0_; hx[0][4 + wv] = m1_;
                                            hx[0][8 + wv] = m2_; hx[0][12 + wv] = m3_; });
                PASS(0, 2, if (lane == 0) { mbuf[r * 16 + wv] = m0_;
                                            mbuf[r * 16 + 4 + wv] = m1_;
                                            mbuf[r * 16 + 8 + wv] = m2_;
                                            mbuf[r * 16 + 12 + wv] = m3_; });
                if (tid == 0)
                    __hip_atomic_store(&fA[r], (u32)(t + 1), __ATOMIC_RELEASE,
                                       __HIP_MEMORY_SCOPE_AGENT);
            }
        }
    } else {
        // ---------------- stage B: layers 3-5 + head + splice ----------------
        for (int t = 0; t < TSTEPS; ++t) {
#pragma unroll
            for (int ri = 0; ri < 2; ++ri) {
                const int r = r0 + ri;
                wait_ge(&fA[r], (u32)(t + 1));
                const int tok = tokens[r * TSTEPS + t]; // uniform scalar load
                u64 enew = 0;
                if (wv == 0 && lane < 2) enew = eb[tok * 2 + lane]; // prefetch
                if (wv == 0 && lane < 16) hx[0][lane] = mbuf[r * 16 + lane];
                __syncthreads();
                PASS(0, 0, if (lane == 0) { hx[1][wv] = m0_; hx[1][4 + wv] = m1_;
                                            hx[1][8 + wv] = m2_; hx[1][12 + wv] = m3_; });
                PASS(1, 1, if (lane == 0) { hx[0][wv] = m0_; hx[0][4 + wv] = m1_;
                                            hx[0][8 + wv] = m2_; hx[0][12 + wv] = m3_; });
                PASS(0, 2, if (lane == 0) {
                        hx[1][wv] = m0_;      hx[1][4 + wv] = m1_;
                        hx[1][8 + wv] = m2_;  hx[1][12 + wv] = m3_; // for head
                        xbuf[r * 16 + wv] = m0_;          // carry words 0..13
                        xbuf[r * 16 + 4 + wv] = m1_;
                        xbuf[r * 16 + 8 + wv] = m2_;
                        if (wv < 2) xbuf[r * 16 + 12 + wv] = m3_; });
                // head + log-softmax + loss + embed splice (wave 0); h5 in hx[1]
                if (wv == 0) {
                    u64 ra = hx[1][14], rb = hx[1][15];
                    u64 h0a = hbL[lane * 2 + 0],        h0b = hbL[lane * 2 + 1];
                    u64 h1a = hbL[(lane + 64) * 2 + 0], h1b = hbL[(lane + 64) * 2 + 1];
                    int d0 = 128 - 2 * (__popcll(ra ^ h0a) + __popcll(rb ^ h0b));
                    int d1 = 128 - 2 * (__popcll(ra ^ h1a) + __popcll(rb ^ h1b));
                    float l0 = (float)d0 * (1.0f / 16.0f);
                    float l1 = (float)d1 * (1.0f / 16.0f);
                    float mx = fmaxf(l0, l1);
#pragma unroll
                    for (int s = 32; s >= 1; s >>= 1) mx = fmaxf(mx, __shfl_xor(mx, s));
                    float se = __expf(l0 - mx) + __expf(l1 - mx);
#pragma unroll
                    for (int s = 32; s >= 1; s >>= 1) se += __shfl_xor(se, s);
                    int   tl   = tok & 63;
                    float la   = __shfl(l0, tl);
                    float lb_  = __shfl(l1, tl);
                    float ltok = (tok >> 6) ? lb_ : la;
                    double dl = (double)(mx + __logf(se) - ltok);
                    if (ri == 0) lacc0 += dl; else lacc1 += dl;
                    if (lane < 2) xbuf[r * 16 + 14 + lane] = enew; // read-part splice
                }
                __syncthreads(); // drain wave0's xbuf stores before release
                if (tid == 0)
                    __hip_atomic_store(&fB[r], (u32)(t + 1), __ATOMIC_RELEASE,
                                       __HIP_MEMORY_SCOPE_AGENT);
            }
        }
        if (tid == 0) { losses[r0] = lacc0; losses[r0 + 1] = lacc1; }
    }
}

__global__ void reduce_loss(const double* __restrict__ losses, float* __restrict__ out) {
    int lane = threadIdx.x; // 64 threads, 1 wave
    double v = losses[lane];
#pragma unroll
    for (int s = 32; s >= 1; s >>= 1) v += __shfl_down(v, s);
    if (lane == 0) out[0] = (float)(v * (1.0 / ((double)BATCH * (double)TSTEPS)));
}

extern "C" void kernel_launch(void* const* d_in, const int* in_sizes, int n_in,
                              void* d_out, int out_size, void* d_ws, size_t ws_size,
                              hipStream_t stream) {
    const int*   tokens  = (const int*)d_in[0];   // (64, 512) int32
    const float* initial = (const float*)d_in[1]; // (1024,)
    const float* embed   = (const float*)d_in[2]; // (128, 128)
    const float* ff      = (const float*)d_in[3]; // (6, 1024, 1024)
    const float* head    = (const float*)d_in[4]; // (128, 128)
    const float* thrl    = (const float*)d_in[5]; // (6, 1024)

    char* ws = (char*)d_ws;
    u64*    ffb    = (u64*)ws;
    u64*    eb     = (u64*)(ws + OFF_EB);
    u64*    hb     = (u64*)(ws + OFF_HB);
    double* losses = (double*)(ws + OFF_LOSS);
    u64*    xbuf   = (u64*)(ws + OFF_XBUF);
    u64*    mbuf   = (u64*)(ws + OFF_MBUF);
    u32*    fAf    = (u32*)(ws + OFF_FA);
    u32*    fBf    = (u32*)(ws + OFF_FB);

    // reset handshake flags every call (harness does not re-poison ws)
    hipMemsetAsync(ws + OFF_FA, 0, 512, stream);

    pack_ff<<<384, 256, 0, stream>>>(ff, ffb);
    pack_small<<<1, 256, 0, stream>>>(embed, head, eb, hb);
    brnn_pipe<<<BATCH, THR, 0, stream>>>(tokens, initial, thrl, ffb, eb, hb,
                                         xbuf, mbuf, fAf, fBf, losses);
    reduce_loss<<<1, 64, 0, stream>>>(losses, (float*)d_out);
}